// Round 6
// baseline (857.399 us; speedup 1.0000x reference)
//
#include <hip/hip_runtime.h>
#include <hip/hip_bf16.h>
#include <cstdint>
#include <cstdio>

// ---------------------------------------------------------------------------
// MIGCProcessorELITE on MI355X — R5: k_outproj rebuild.
// R4: outproj 366us @ MfmaUtil 13.5%, occ 15% (grid-limited), 2 barriers per
// 8 MFMAs, B re-staged 9x. Now: 768-thread blocks, 3 wave-groups x 4 waves on
// one 64x128 tile; B staged ONCE per K-step shared by all 3 groups; BK=64
// (16 MFMA/wave/step); per-group gm-weighted partials combined in-LDS.
// Attention kernels unchanged from R3/R4 (attnl V-from-LDS fix: 845us total).
// ---------------------------------------------------------------------------

#define S_LEN 4096
#define CH    1280
#define CCH   768
#define NHEAD 8
#define HD    160
#define NSTR  9     // 1 + STREAMS
#define NLOC  8     // STREAMS (local branches)
#define GK    77    // global ctx keys
#define LKEY  257   // local keys
// per-(stream,head) block sizes (bytes)
#define KGB   25600   // global K: 80 rows x 160 d x 2
#define VGB   30720   // global V^T: 160 d x 96 keys x 2
#define KLB   87040   // local K: 272 rows x 160 d x 2
#define VLB   102400  // local V^T: 5 chunks x [160 d][64 keys] x 2, swizzled

typedef float  f32x4  __attribute__((ext_vector_type(4)));
typedef __bf16 bf16x8 __attribute__((ext_vector_type(8)));

#define MFMA16(a, b, c) __builtin_amdgcn_mfma_f32_16x16x32_bf16(a, b, c, 0, 0, 0)

static __device__ __forceinline__ short f2b(float f) {
  union { float f; uint32_t u; } v; v.f = f;
  uint32_t b = v.u + 0x7FFFu + ((v.u >> 16) & 1u);  // RNE
  return (short)(b >> 16);
}
static __device__ __forceinline__ float b2f(short s) {
  union { uint32_t u; float f; } v; v.u = ((uint32_t)(uint16_t)s) << 16;
  return v.f;
}
static __device__ __forceinline__ bf16x8 ldb8(const short* p) {
  return *reinterpret_cast<const bf16x8*>(p);
}
static __device__ __forceinline__ void gload16(const short* g, short* l) {
  // async global->LDS, 16B/lane, LDS dest = wave-uniform base + lane*16
  __builtin_amdgcn_global_load_lds((const __attribute__((address_space(1))) void*)g,
                                   (__attribute__((address_space(3))) void*)l, 16, 0, 0);
}

// --------------------------- f32 -> bf16 flat convert ----------------------
__global__ void k_conv_flat(const float* __restrict__ src, short* __restrict__ dst, int n8) {
  int idx = blockIdx.x * 256 + threadIdx.x;
  if (idx >= n8) return;
  size_t base = (size_t)idx * 8;
  const float4* s4 = reinterpret_cast<const float4*>(src + base);
  float4 a = s4[0], b = s4[1];
  short o[8] = { f2b(a.x), f2b(a.y), f2b(a.z), f2b(a.w),
                 f2b(b.x), f2b(b.y), f2b(b.z), f2b(b.w) };
  *reinterpret_cast<ulonglong2*>(dst + base) = *reinterpret_cast<ulonglong2*>(o);
}

// ----------------- weight transpose + convert (W[k][n] -> WT[n][k]) --------
struct TrParams {
  const float* src[8];
  short* dst[8];
  int rows[8];          // K-dim of each weight (cols always 1280)
};
__global__ void k_conv_tr(TrParams p) {
  int z = blockIdx.z;
  int rows = p.rows[z];
  int r0 = blockIdx.y * 32;
  if (r0 >= rows) return;
  const float* src = p.src[z];
  short* dst = p.dst[z];
  __shared__ float tile[32][33];
  int tx = threadIdx.x & 31, ty = threadIdx.x >> 5;  // 32 x 8
  int c = blockIdx.x * 32 + tx;
#pragma unroll
  for (int it = 0; it < 4; ++it)
    tile[ty + it * 8][tx] = src[(size_t)(r0 + ty + it * 8) * 1280 + c];
  __syncthreads();
#pragma unroll
  for (int it = 0; it < 4; ++it) {
    int n = blockIdx.x * 32 + ty + it * 8;
    dst[(size_t)n * rows + r0 + tx] = f2b(tile[tx][ty + it * 8]);
  }
}

// ------------------- bbox masks -> gm[8][4096] + denom[4096] ---------------
__global__ void k_gm(const float* __restrict__ bbox, float* __restrict__ gm,
                     float* __restrict__ dnm) {
  int s = blockIdx.x * 256 + threadIdx.x;
  if (s >= 4096) return;
  int y = s >> 6, x = s & 63;
  gm[s] = 1.0f;
  float dsum = 1.0f;
#pragma unroll
  for (int i = 0; i < 7; ++i) {
    float x0 = bbox[i * 4 + 0], y0 = bbox[i * 4 + 1];
    float x1 = bbox[i * 4 + 2], y1 = bbox[i * 4 + 3];
    float wmin = floorf(1024.f * x0), hmin = floorf(1024.f * y0);
    float wmax = floorf(1024.f * x1), hmax = floorf(1024.f * y1);
    float r = 0.f, cc = 0.f;
#pragma unroll
    for (int t = 0; t < 4; ++t) {
      const int off[4] = {3, 4, 11, 12};
      float py = (float)(16 * y + off[t]);
      float px = (float)(16 * x + off[t]);
      r  += (py >= hmin && py < hmax) ? 0.25f : 0.f;
      cc += (px >= wmin && px < wmax) ? 0.25f : 0.f;
    }
    float val = r * cc * 10.0f;
    gm[(i + 1) * 4096 + s] = val;
    dsum += val;
  }
  dnm[s] = dsum + 1e-6f;
}

// ---------------------- Q projection: 8192x1280 @ 1280x1280 ----------------
__global__ __launch_bounds__(256) void k_qproj(const short* __restrict__ A,
                                               const short* __restrict__ BT,
                                               short* __restrict__ Cq) {
  __shared__ short As[128 * 32];
  __shared__ short Bs[128 * 32];
  int tid = threadIdx.x, lane = tid & 63, wid = tid >> 6;
  int m0 = blockIdx.x * 128, n0 = blockIdx.y * 128;
  int wr = wid >> 1, wc = wid & 1;
  int colc = lane & 15, g4 = lane >> 4;
  int ar = lane >> 2, ac = (lane & 3) * 8;
  f32x4 acc[4][4] = {};
  for (int kt = 0; kt < 40; ++kt) {
    int k0 = kt * 32;
#pragma unroll
    for (int i = 0; i < 2; ++i) {
      int row = wid * 16 + i * 64 + ar;
      gload16(A + (size_t)(m0 + row) * 1280 + k0 + ac, &As[wid * 512 + i * 2048]);
      gload16(BT + (size_t)(n0 + row) * 1280 + k0 + ac, &Bs[wid * 512 + i * 2048]);
    }
    __syncthreads();
    bf16x8 af[4], bfr[4];
#pragma unroll
    for (int m = 0; m < 4; ++m)
      af[m] = ldb8(&As[(wr * 64 + 16 * m + colc) * 32 + 8 * g4]);
#pragma unroll
    for (int n = 0; n < 4; ++n)
      bfr[n] = ldb8(&Bs[(wc * 64 + 16 * n + colc) * 32 + 8 * g4]);
#pragma unroll
    for (int m = 0; m < 4; ++m)
#pragma unroll
      for (int n = 0; n < 4; ++n)
        acc[m][n] = MFMA16(af[m], bfr[n], acc[m][n]);
    __syncthreads();
  }
#pragma unroll
  for (int m = 0; m < 4; ++m)
#pragma unroll
    for (int n = 0; n < 4; ++n)
#pragma unroll
      for (int r = 0; r < 4; ++r) {
        int row = m0 + wr * 64 + 16 * m + 4 * g4 + r;
        int col = n0 + wc * 64 + 16 * n + colc;
        Cq[(size_t)row * 1280 + col] = f2b(acc[m][n][r]);
      }
}

// ------------- ctx + local K/V projections (1-wave blocks, 16x64 tiles) ----
__global__ __launch_bounds__(64) void k_projkv(
    const short* __restrict__ ctxb, const short* __restrict__ lfb,
    const short* __restrict__ WkT, const short* __restrict__ WvT,
    const short* __restrict__ WkgT, const short* __restrict__ WvgT,
    const short* __restrict__ WklT, const short* __restrict__ WvlT,
    short* __restrict__ kbuf, short* __restrict__ vTb,
    short* __restrict__ klbuf, short* __restrict__ vlTb,
    const int* __restrict__ lidx) {
  int z = blockIdx.z, yt = blockIdx.y, c0 = blockIdx.x * 64;
  int lane = threadIdx.x;
  int colc = lane & 15, g4 = lane >> 4;
  const short *Ab, *Wk_, *Wv_;
  int R;
  if (z < NSTR) {
    if (yt >= 5) return;
    R = GK;
    Ab = ctxb + (size_t)z * GK * CCH;
    bool useg = (z > 0) && (lidx[z - 1] >= 0);
    Wk_ = useg ? WkgT : WkT;
    Wv_ = useg ? WvgT : WvT;
  } else {
    R = LKEY;
    Ab = lfb + (size_t)(z - NSTR) * LKEY * CCH;
    Wk_ = WklT; Wv_ = WvlT;
  }
  int rowA = yt * 16 + colc;
  if (rowA >= R) rowA = R - 1;
  f32x4 ak[4] = {}, av[4] = {};
  for (int kk = 0; kk < 24; ++kk) {
    bf16x8 af = ldb8(&Ab[(size_t)rowA * CCH + kk * 32 + 8 * g4]);
#pragma unroll
    for (int nt = 0; nt < 4; ++nt) {
      bf16x8 bk = ldb8(&Wk_[(size_t)(c0 + 16 * nt + colc) * CCH + kk * 32 + 8 * g4]);
      ak[nt] = MFMA16(af, bk, ak[nt]);
      bf16x8 bv = ldb8(&Wv_[(size_t)(c0 + 16 * nt + colc) * CCH + kk * 32 + 8 * g4]);
      av[nt] = MFMA16(af, bv, av[nt]);
    }
  }
#pragma unroll
  for (int nt = 0; nt < 4; ++nt)
#pragma unroll
    for (int r = 0; r < 4; ++r) {
      int row = yt * 16 + 4 * g4 + r;
      if (row < R) {
        int col = c0 + 16 * nt + colc;
        int hh = col / 160, dd = col % 160;
        short kv = f2b(ak[nt][r]), vv = f2b(av[nt][r]);
        if (z < NSTR) {
          size_t kb = (size_t)(z * 8 + hh) * KGB +
                      (size_t)((row * 320 + 2 * dd) ^ ((row & 7) << 4));
          *(short*)((char*)kbuf + kb) = kv;
          size_t vb = (size_t)(z * 8 + hh) * VGB +
                      (size_t)((dd * 192 + 2 * row) ^ ((dd & 7) << 4));
          *(short*)((char*)vTb + vb) = vv;
        } else {
          int ii = z - NSTR;
          size_t kb = (size_t)(ii * 8 + hh) * KLB +
                      (size_t)((row * 320 + 2 * dd) ^ ((row & 7) << 4));
          *(short*)((char*)klbuf + kb) = kv;
          // V^T in 64-key chunks: [chunk][d][unit^(d&7)][key&7], contiguous
          // per chunk so k_attnl can global_load_lds it linearly.
          int cc = row >> 6, lc = row & 63;
          int unit = lc >> 3, wi = lc & 7;
          vlTb[((size_t)(ii * 8 + hh) * 5 + cc) * 10240 + dd * 64 +
               ((unit ^ (dd & 7)) << 3) + wi] = vv;
        }
      }
    }
}

// ----------------------------- global attention ----------------------------
__global__ __launch_bounds__(256) void k_attng(
    const short* __restrict__ q, const short* __restrict__ kb_,
    const short* __restrict__ vT, short* __restrict__ abh,
    float* __restrict__ mg, const int* __restrict__ lidx) {
  int chunk = blockIdx.x, h = blockIdx.y, b = blockIdx.z;
  int tid = threadIdx.x, lane = tid & 63, wid = tid >> 6;
  __shared__ short KV[28160];                 // K: [0,12800) V: [12800,28160)
  alignas(16) __shared__ short pbuf[4][16 * 104];
  const short* qb = q + (b > 0 ? (size_t)S_LEN * CH : 0) + h * HD;
  const short* kg = kb_ + (size_t)(b * 8 + h) * (KGB / 2);
  const short* vg = vT + (size_t)(b * 8 + h) * (VGB / 2);
  for (int j = wid; j < 55; j += 4) {
    if (j < 25) gload16(kg + j * 512 + (lane << 3), &KV[j * 512]);
    else        gload16(vg + (j - 25) * 512 + (lane << 3), &KV[12800 + (j - 25) * 512]);
  }
  __syncthreads();
  short* pw = pbuf[wid];
  int colc = lane & 15, g4 = lane >> 4;
  int xorv = (colc & 7) << 4;
  const float scale = 0.07905694150420949f;  // 1/sqrt(160)
  int li[8];
#pragma unroll
  for (int i = 0; i < 8; ++i) li[i] = lidx[i];

  for (int g = 0; g < 8; ++g) {
    int s0 = chunk * 512 + wid * 128 + g * 16;
    bf16x8 aq[5];
#pragma unroll
    for (int kk = 0; kk < 5; ++kk)
      aq[kk] = ldb8(&qb[(size_t)(s0 + colc) * CH + kk * 32 + 8 * g4]);
    f32x4 acc[5] = {};
#pragma unroll
    for (int nt = 0; nt < 5; ++nt)
#pragma unroll
      for (int kk = 0; kk < 5; ++kk) {
        int kbx = (((16 * nt + colc) * 320 + 64 * kk + 16 * g4) ^ xorv) >> 1;
        acc[nt] = MFMA16(aq[kk], ldb8(&KV[kbx]), acc[nt]);
      }
    // ---- softmax over 77 keys ----
    float rmax[4] = {-1e30f, -1e30f, -1e30f, -1e30f};
#pragma unroll
    for (int nt = 0; nt < 5; ++nt) {
      bool v = (16 * nt + colc) < GK;
#pragma unroll
      for (int r = 0; r < 4; ++r) {
        float lg = v ? acc[nt][r] * scale : -1e30f;
        acc[nt][r] = lg;
        rmax[r] = fmaxf(rmax[r], lg);
      }
    }
#pragma unroll
    for (int r = 0; r < 4; ++r)
#pragma unroll
      for (int m = 1; m < 16; m <<= 1) rmax[r] = fmaxf(rmax[r], __shfl_xor(rmax[r], m, 64));
    float rsum[4] = {0.f, 0.f, 0.f, 0.f};
#pragma unroll
    for (int nt = 0; nt < 5; ++nt) {
      bool v = (16 * nt + colc) < GK;
#pragma unroll
      for (int r = 0; r < 4; ++r) {
        float p = v ? __expf(acc[nt][r] - rmax[r]) : 0.0f;
        acc[nt][r] = p;
        rsum[r] += p;
      }
    }
#pragma unroll
    for (int r = 0; r < 4; ++r)
#pragma unroll
      for (int m = 1; m < 16; m <<= 1) rsum[r] += __shfl_xor(rsum[r], m, 64);
    float rinv[4];
#pragma unroll
    for (int r = 0; r < 4; ++r) rinv[r] = 1.0f / rsum[r];
#pragma unroll
    for (int nt = 0; nt < 5; ++nt)
#pragma unroll
      for (int r = 0; r < 4; ++r) acc[nt][r] *= rinv[r];
    // ---- gate capture (stream 0): m[i][h][s] = probs[s][local_index[i]]
    if (b == 0) {
#pragma unroll
      for (int i = 0; i < 8; ++i) {
        int l_ = li[i];
        float pv[4] = {0.f, 0.f, 0.f, 0.f};
#pragma unroll
        for (int nt = 0; nt < 5; ++nt)
#pragma unroll
          for (int r = 0; r < 4; ++r)
            pv[r] = (nt == (l_ >> 4)) ? acc[nt][r] : pv[r];
        if ((l_ & 15) == colc) {
#pragma unroll
          for (int r = 0; r < 4; ++r)
            mg[(size_t)(i * NHEAD + h) * 4096 + s0 + 4 * g4 + r] = pv[r];
        }
      }
    }
    // ---- P -> per-wave LDS (96 cols, tile 5 zero-padded) ----
#pragma unroll
    for (int nt = 0; nt < 6; ++nt)
#pragma unroll
      for (int r = 0; r < 4; ++r) {
        short vb = (nt < 5) ? f2b(acc[nt][r]) : (short)0;
        pw[(4 * g4 + r) * 104 + 16 * nt + colc] = vb;
      }
    // ---- PV from LDS ----
    f32x4 acc2[10] = {};
#pragma unroll
    for (int kk2 = 0; kk2 < 3; ++kk2) {
      bf16x8 ap = ldb8(&pw[colc * 104 + kk2 * 32 + 8 * g4]);
#pragma unroll
      for (int nt2 = 0; nt2 < 10; ++nt2) {
        int vbx = 12800 + (((((16 * nt2 + colc) * 192) + 64 * kk2 + 16 * g4) ^ xorv) >> 1);
        acc2[nt2] = MFMA16(ap, ldb8(&KV[vbx]), acc2[nt2]);
      }
    }
#pragma unroll
    for (int nt2 = 0; nt2 < 10; ++nt2)
#pragma unroll
      for (int r = 0; r < 4; ++r) {
        int s = s0 + 4 * g4 + r;
        abh[((size_t)b * S_LEN + s) * CH + h * HD + 16 * nt2 + colc] = f2b(acc2[nt2][r]);
      }
  }
}

// --------------------- gate max reduce: mmax[i] = max(mg[i]) ---------------
__global__ __launch_bounds__(256) void k_mmax(const float* __restrict__ mg,
                                              float* __restrict__ mmx) {
  int i = blockIdx.x;
  __shared__ float red[4];
  float m = 0.f;
  for (int t = threadIdx.x; t < 32768; t += 256) m = fmaxf(m, mg[(size_t)i * 32768 + t]);
#pragma unroll
  for (int msk = 32; msk >= 1; msk >>= 1) m = fmaxf(m, __shfl_xor(m, msk, 64));
  if ((threadIdx.x & 63) == 0) red[threadIdx.x >> 6] = m;
  __syncthreads();
  if (threadIdx.x == 0)
    mmx[i] = fmaxf(fmaxf(red[0], red[1]), fmaxf(red[2], red[3]));
}

// ------------------------------ local attention ----------------------------
// K staged once (87 KB swizzled); V^T double-buffered in LDS as 5 x 20 KB
// pre-swizzled 64-key chunks. pbuf per-wave 16x72. 8 waves, 8 slabs.
__global__ __launch_bounds__(512) void k_attnl(
    const short* __restrict__ q, const short* __restrict__ klb_,
    const short* __restrict__ vlT, short* __restrict__ abh,
    const float* __restrict__ mg, const float* __restrict__ mmx) {
  int chunk = blockIdx.x, h = blockIdx.y, i = blockIdx.z;
  int tid = threadIdx.x, lane = tid & 63, wid = tid >> 6;
  __shared__ short Klds[43520];               // 272 rows x 160 d, swizzled
  __shared__ short Vlds[2][10240];            // 2 x [160 d][64 keys], swizzled
  alignas(16) __shared__ short pbuf[8][16 * 72];
  const short* qb = q + (size_t)S_LEN * CH + h * HD;  // batch-1 Q
  const short* kg = klb_ + (size_t)(i * 8 + h) * (KLB / 2);
  const short* vtb = vlT + (size_t)(i * 8 + h) * (VLB / 2);
  for (int j = wid; j < 85; j += 8) gload16(kg + j * 512 + (lane << 3), &Klds[j * 512]);
  // prologue: stage V chunk 0 into buffer 0
  for (int u0 = wid * 64; u0 < 1280; u0 += 512)
    gload16(vtb + (u0 << 3) + (lane << 3), &Vlds[0][u0 << 3]);
  __syncthreads();
  short* pw = pbuf[wid];
  int colc = lane & 15, g4 = lane >> 4;
  int xorv = (colc & 7) << 4;
  const float scale = 0.07905694150420949f;
  float minv = 1.0f / mmx[i];
  int cur = 0;

  for (int g = 0; g < 8; ++g) {
    int s0 = chunk * 1024 + wid * 128 + g * 16;
    bf16x8 aq[5];
#pragma unroll
    for (int kk = 0; kk < 5; ++kk)
      aq[kk] = ldb8(&qb[(size_t)(s0 + colc) * CH + kk * 32 + 8 * g4]);
    f32x4 acc[17] = {};
#pragma unroll
    for (int nt = 0; nt < 17; ++nt)
#pragma unroll
      for (int kk = 0; kk < 5; ++kk) {
        int kbx = (((16 * nt + colc) * 320 + 64 * kk + 16 * g4) ^ xorv) >> 1;
        acc[nt] = MFMA16(aq[kk], ldb8(&Klds[kbx]), acc[nt]);
      }
    float rmax[4] = {-1e30f, -1e30f, -1e30f, -1e30f};
#pragma unroll
    for (int nt = 0; nt < 17; ++nt) {
      bool v = (16 * nt + colc) < LKEY;
#pragma unroll
      for (int r = 0; r < 4; ++r) {
        float lg = v ? acc[nt][r] * scale : -1e30f;
        acc[nt][r] = lg;
        rmax[r] = fmaxf(rmax[r], lg);
      }
    }
#pragma unroll
    for (int r = 0; r < 4; ++r)
#pragma unroll
      for (int m = 1; m < 16; m <<= 1) rmax[r] = fmaxf(rmax[r], __shfl_xor(rmax[r], m, 64));
    float rsum[4] = {0.f, 0.f, 0.f, 0.f};
#pragma unroll
    for (int nt = 0; nt < 17; ++nt) {
      bool v = (16 * nt + colc) < LKEY;
#pragma unroll
      for (int r = 0; r < 4; ++r) {
        float p = v ? __expf(acc[nt][r] - rmax[r]) : 0.0f;
        acc[nt][r] = p;
        rsum[r] += p;
      }
    }
#pragma unroll
    for (int r = 0; r < 4; ++r)
#pragma unroll
      for (int m = 1; m < 16; m <<= 1) rsum[r] += __shfl_xor(rsum[r], m, 64);
    float rinv[4];
#pragma unroll
    for (int r = 0; r < 4; ++r) rinv[r] = 1.0f / rsum[r];

    // PV over 5 x 64-key chunks, double-buffered V in LDS.
    f32x4 acc2[10] = {};
#pragma unroll
    for (int c = 0; c < 5; ++c) {
      {
        const short* srcv = vtb + (c == 4 ? 0 : (c + 1)) * 10240;
        for (int u0 = wid * 64; u0 < 1280; u0 += 512)
          gload16(srcv + (u0 << 3) + (lane << 3), &Vlds[cur ^ 1][u0 << 3]);
      }
#pragma unroll
      for (int t = 0; t < 4; ++t) {
        int nt = 4 * c + t;
#pragma unroll
        for (int r = 0; r < 4; ++r) {
          short vb = (nt < 17) ? f2b(acc[nt][r] * rinv[r]) : (short)0;
          pw[(4 * g4 + r) * 72 + 16 * t + colc] = vb;
        }
      }
#pragma unroll
      for (int kc = 0; kc < 2; ++kc) {
        bf16x8 ap = ldb8(&pw[colc * 72 + kc * 32 + 8 * g4]);
#pragma unroll
        for (int nt2 = 0; nt2 < 10; ++nt2) {
          bf16x8 bv = ldb8(&Vlds[cur][(16 * nt2 + colc) * 64 +
                                      ((((kc << 2) + g4) ^ (colc & 7)) << 3)]);
          acc2[nt2] = MFMA16(ap, bv, acc2[nt2]);
        }
      }
      __syncthreads();
      cur ^= 1;
    }
    float gv[4];
#pragma unroll
    for (int r = 0; r < 4; ++r)
      gv[r] = mg[(size_t)(i * NHEAD + h) * 4096 + s0 + 4 * g4 + r] * minv;
#pragma unroll
    for (int nt2 = 0; nt2 < 10; ++nt2)
#pragma unroll
      for (int r = 0; r < 4; ++r) {
        int s = s0 + 4 * g4 + r;
        size_t idx = ((size_t)(1 + i) * S_LEN + s) * CH + h * HD + 16 * nt2 + colc;
        float oldv = b2f(abh[idx]);
        abh[idx] = f2b(0.5f * oldv + 0.5f * gv[r] * acc2[nt2][r]);
      }
  }
}

// ------------- out projection + fused bbox fuser epilogue ------------------
// R5: 768 threads = 3 wave-groups x 4 waves on a 64x128 tile. Group g handles
// streams {3g,3g+1,3g+2} (pass p: stream 3g+p). Per K-step (BK=64): B staged
// ONCE (shared), 3 per-group A tiles; 16 MFMA/wave between 2 barriers.
// gm-weighted partials combined through LDS at block end (overlay on stage).
__global__ __launch_bounds__(768) void k_outproj(
    const short* __restrict__ abh, const short* __restrict__ WoT,
    const float* __restrict__ bout, const float* __restrict__ gm,
    const float* __restrict__ dnm, float* __restrict__ outp) {
  __shared__ __align__(16) char smem[40960];
  short* As = (short*)smem;             // 3 x [64][64] shorts (24 KB)
  short* Bs = (short*)(smem + 24576);   // [128][64] shorts (16 KB)
  float* comb = (float*)smem;           // epilogue overlay [64][128] f32 (32 KB)
  int tid = threadIdx.x, lane = tid & 63, wid = tid >> 6;
  int g = wid >> 2, gw4 = wid & 3;      // wave-group, wave-in-group
  int wr = gw4 >> 1, wc = gw4 & 1;      // 2x2 wave layout over 64x128
  int s0 = blockIdx.x * 64, n0 = blockIdx.y * 128;
  int colc = lane & 15, g4 = lane >> 4;
  int ar = lane >> 3, ac = (lane & 7) * 8;   // stage: 8 rows x 64 cols per instr
  float bo[4];
#pragma unroll
  for (int nt = 0; nt < 4; ++nt) bo[nt] = bout[n0 + wc * 64 + 16 * nt + colc];
  f32x4 fac[2][4] = {};
#pragma unroll 1
  for (int p = 0; p < 3; ++p) {
    int b = 3 * g + p;
    f32x4 acc[2][4] = {};
    for (int kt = 0; kt < 20; ++kt) {
      int k0 = kt * 64;
      // stage: 24 A-instrs (3 groups x 8) + 16 B-instrs over 12 waves
      for (int j = wid; j < 40; j += 12) {
        if (j < 24) {
          int g2 = j >> 3, r8 = j & 7;
          int bb = 3 * g2 + p;
          gload16(abh + ((size_t)bb * S_LEN + s0 + r8 * 8 + ar) * CH + k0 + ac,
                  As + g2 * 4096 + r8 * 512);
        } else {
          int jb = j - 24;
          gload16(WoT + (size_t)(n0 + jb * 8 + ar) * 1280 + k0 + ac, Bs + jb * 512);
        }
      }
      __syncthreads();
      bf16x8 af[2][2], bfr[4][2];
#pragma unroll
      for (int mt = 0; mt < 2; ++mt)
#pragma unroll
        for (int kk = 0; kk < 2; ++kk)
          af[mt][kk] = ldb8(&As[g * 4096 + (wr * 32 + 16 * mt + colc) * 64 + kk * 32 + 8 * g4]);
#pragma unroll
      for (int nt = 0; nt < 4; ++nt)
#pragma unroll
        for (int kk = 0; kk < 2; ++kk)
          bfr[nt][kk] = ldb8(&Bs[(wc * 64 + 16 * nt + colc) * 64 + kk * 32 + 8 * g4]);
#pragma unroll
      for (int mt = 0; mt < 2; ++mt)
#pragma unroll
        for (int nt = 0; nt < 4; ++nt)
#pragma unroll
          for (int kk = 0; kk < 2; ++kk)
            acc[mt][nt] = MFMA16(af[mt][kk], bfr[nt][kk], acc[mt][nt]);
      __syncthreads();
    }
    if (b == 0) {
      // uncond stream: direct output with bias (only group 0, pass 0)
#pragma unroll
      for (int mt = 0; mt < 2; ++mt)
#pragma unroll
        for (int nt = 0; nt < 4; ++nt)
#pragma unroll
          for (int r = 0; r < 4; ++r) {
            int s = s0 + wr * 32 + 16 * mt + 4 * g4 + r;
            int c = n0 + wc * 64 + 16 * nt + colc;
            outp[(size_t)s * CH + c] = acc[mt][nt][r] + bo[nt];
          }
    } else {
      float gwv[2][4];
#pragma unroll
      for (int mt = 0; mt < 2; ++mt)
#pragma unroll
        for (int r = 0; r < 4; ++r)
          gwv[mt][r] = gm[(size_t)(b - 1) * 4096 + s0 + wr * 32 + 16 * mt + 4 * g4 + r];
#pragma unroll
      for (int mt = 0; mt < 2; ++mt)
#pragma unroll
        for (int nt = 0; nt < 4; ++nt)
#pragma unroll
          for (int r = 0; r < 4; ++r)
            fac[mt][nt][r] += gwv[mt][r] * acc[mt][nt][r];
    }
  }
  // combine group1/group2 partials into group0 via LDS overlay
#pragma unroll 1
  for (int src = 1; src <= 2; ++src) {
    if (g == src) {
#pragma unroll
      for (int mt = 0; mt < 2; ++mt)
#pragma unroll
        for (int nt = 0; nt < 4; ++nt)
#pragma unroll
          for (int r = 0; r < 4; ++r)
            comb[(wr * 32 + 16 * mt + 4 * g4 + r) * 128 + wc * 64 + 16 * nt + colc] =
                fac[mt][nt][r];
    }
    __syncthreads();
    if (g == 0) {
#pragma unroll
      for (int mt = 0; mt < 2; ++mt)
#pragma unroll
        for (int nt = 0; nt < 4; ++nt)
#pragma unroll
          for (int r = 0; r < 4; ++r)
            fac[mt][nt][r] +=
                comb[(wr * 32 + 16 * mt + 4 * g4 + r) * 128 + wc * 64 + 16 * nt + colc];
    }
    __syncthreads();
  }
  if (g == 0) {
#pragma unroll
    for (int mt = 0; mt < 2; ++mt)
#pragma unroll
      for (int r = 0; r < 4; ++r) {
        int s = s0 + wr * 32 + 16 * mt + 4 * g4 + r;
        float dn = dnm[s];
        float sw = dn - 1e-6f;
        float inv = 1.0f / dn;
#pragma unroll
        for (int nt = 0; nt < 4; ++nt) {
          int c = n0 + wc * 64 + 16 * nt + colc;
          outp[(size_t)(S_LEN + s) * CH + c] = (fac[mt][nt][r] + bo[nt] * sw) * inv;
        }
      }
  }
}

// ---------------------------------------------------------------------------
extern "C" void kernel_launch(void* const* d_in, const int* in_sizes, int n_in,
                              void* d_out, int out_size, void* d_ws, size_t ws_size,
                              hipStream_t stream) {
  const float* hs   = (const float*)d_in[0];
  const float* ctx  = (const float*)d_in[1];
  const float* lf   = (const float*)d_in[2];
  const float* bbox = (const float*)d_in[3];
  const float* Wq   = (const float*)d_in[4];
  const float* Wk   = (const float*)d_in[5];
  const float* Wv   = (const float*)d_in[6];
  const float* Wkg  = (const float*)d_in[7];
  const float* Wvg  = (const float*)d_in[8];
  const float* Wkl  = (const float*)d_in[9];
  const float* Wvl  = (const float*)d_in[10];
  const float* Wout = (const float*)d_in[11];
  const float* bo   = (const float*)d_in[12];
  const int*   lidx = (const int*)d_in[13];
  float* outp = (float*)d_out;

  char* w = (char*)d_ws;
  size_t off = 0;
  auto carve = [&](size_t bytes) {
    char* p = w + off;
    off = (off + bytes + 255) & ~(size_t)255;
    return p;
  };
  short* hsb   = (short*)carve(2ull * S_LEN * CH * 2);
  short* qbuf  = (short*)carve(2ull * S_LEN * CH * 2);
  short* WqT   = (short*)carve(1280ull * 1280 * 2);
  short* WoT   = (short*)carve(1280ull * 1280 * 2);
  short* WkT   = (short*)carve(1280ull * 768 * 2);
  short* WvT   = (short*)carve(1280ull * 768 * 2);
  short* WkgT  = (short*)carve(1280ull * 768 * 2);
  short* WvgT  = (short*)carve(1280ull * 768 * 2);
  short* WklT  = (short*)carve(1280ull * 768 * 2);
  short* WvlT  = (short*)carve(1280ull * 768 * 2);
  short* ctxb  = (short*)carve((size_t)NSTR * GK * CCH * 2);
  short* lfb   = (short*)carve((size_t)NLOC * LKEY * CCH * 2);
  short* kbuf  = (short*)carve((size_t)NSTR * 8 * KGB);
  short* klbuf = (short*)carve((size_t)NLOC * 8 * KLB);
  short* vTb   = (short*)carve((size_t)NSTR * 8 * VGB);
  short* vlTb  = (short*)carve((size_t)NLOC * 8 * VLB);
  short* abh   = (short*)carve((size_t)NSTR * S_LEN * CH * 2);
  float* mg    = (float*)carve(8ull * 8 * 4096 * 4);
  float* mmx   = (float*)carve(256);
  float* gmb   = (float*)carve(8ull * 4096 * 4);
  float* dnm   = (float*)carve(4096ull * 4);
  (void)carve(65536);  // slack
  if (off > ws_size) {
    fprintf(stderr, "MIGC kernel: ws too small, need %zu have %zu\n", off, ws_size);
    return;
  }

  hipMemsetAsync(vTb, 0, (size_t)NSTR * 8 * VGB, stream);
  hipMemsetAsync(vlTb, 0, (size_t)NLOC * 8 * VLB, stream);

  k_conv_flat<<<5120, 256, 0, stream>>>(hs, hsb, 1310720);
  k_conv_flat<<<260, 256, 0, stream>>>(ctx, ctxb, 66528);
  k_conv_flat<<<771, 256, 0, stream>>>(lf, lfb, 197376);

  TrParams tp;
  const float* srcs[8] = {Wq, Wk, Wv, Wkg, Wvg, Wkl, Wvl, Wout};
  short* dsts[8] = {WqT, WkT, WvT, WkgT, WvgT, WklT, WvlT, WoT};
  int rws[8] = {1280, 768, 768, 768, 768, 768, 768, 1280};
  for (int i = 0; i < 8; ++i) { tp.src[i] = srcs[i]; tp.dst[i] = dsts[i]; tp.rows[i] = rws[i]; }
  k_conv_tr<<<dim3(40, 40, 8), 256, 0, stream>>>(tp);

  k_gm<<<16, 256, 0, stream>>>(bbox, gmb, dnm);
  k_qproj<<<dim3(64, 10), 256, 0, stream>>>(hsb, WqT, qbuf);
  k_projkv<<<dim3(20, 17, 17), 64, 0, stream>>>(ctxb, lfb, WkT, WvT, WkgT, WvgT,
                                                WklT, WvlT, kbuf, vTb, klbuf, vlTb, lidx);
  k_attng<<<dim3(8, 8, 9), 256, 0, stream>>>(qbuf, kbuf, vTb, abh, mg, lidx);
  k_mmax<<<8, 256, 0, stream>>>(mg, mmx);
  k_attnl<<<dim3(4, 8, 8), 512, 0, stream>>>(qbuf, klbuf, vlTb, abh, mg, mmx);
  k_outproj<<<dim3(64, 10), 768, 0, stream>>>(abh, WoT, bo, gmb, dnm, outp);
}

// Round 7
// 664.785 us; speedup vs baseline: 1.2897x; 1.2897x over previous
//
#include <hip/hip_runtime.h>
#include <hip/hip_bf16.h>
#include <cstdint>
#include <cstdio>

// ---------------------------------------------------------------------------
// MIGCProcessorELITE on MI355X — R6: k_outproj conflict fix + B-reuse.
// R5 post-mortem: 128-B-stride LDS tiles -> 16-lane/4-bank ds_read conflicts
// (6.7e7 cyc) and B re-read per pass; MfmaUtil stuck 13%. Now: XOR swizzle
// (pre-swizzled global source + XOR'd ds_read, m173 both-sides pattern),
// all 9 A-tiles staged per K-step (72KB) + B once (16KB), pass-loop inside:
// 20 b128 -> 48 MFMA per wave per K-step; 2 barriers per K-step (40/block).
// ---------------------------------------------------------------------------

#define S_LEN 4096
#define CH    1280
#define CCH   768
#define NHEAD 8
#define HD    160
#define NSTR  9     // 1 + STREAMS
#define NLOC  8     // STREAMS (local branches)
#define GK    77    // global ctx keys
#define LKEY  257   // local keys
// per-(stream,head) block sizes (bytes)
#define KGB   25600   // global K: 80 rows x 160 d x 2
#define VGB   30720   // global V^T: 160 d x 96 keys x 2
#define KLB   87040   // local K: 272 rows x 160 d x 2
#define VLB   102400  // local V^T: 5 chunks x [160 d][64 keys] x 2, swizzled

typedef float  f32x4  __attribute__((ext_vector_type(4)));
typedef __bf16 bf16x8 __attribute__((ext_vector_type(8)));

#define MFMA16(a, b, c) __builtin_amdgcn_mfma_f32_16x16x32_bf16(a, b, c, 0, 0, 0)

static __device__ __forceinline__ short f2b(float f) {
  union { float f; uint32_t u; } v; v.f = f;
  uint32_t b = v.u + 0x7FFFu + ((v.u >> 16) & 1u);  // RNE
  return (short)(b >> 16);
}
static __device__ __forceinline__ float b2f(short s) {
  union { uint32_t u; float f; } v; v.u = ((uint32_t)(uint16_t)s) << 16;
  return v.f;
}
static __device__ __forceinline__ bf16x8 ldb8(const short* p) {
  return *reinterpret_cast<const bf16x8*>(p);
}
static __device__ __forceinline__ void gload16(const short* g, short* l) {
  // async global->LDS, 16B/lane, LDS dest = wave-uniform base + lane*16
  __builtin_amdgcn_global_load_lds((const __attribute__((address_space(1))) void*)g,
                                   (__attribute__((address_space(3))) void*)l, 16, 0, 0);
}

// --------------------------- f32 -> bf16 flat convert ----------------------
__global__ void k_conv_flat(const float* __restrict__ src, short* __restrict__ dst, int n8) {
  int idx = blockIdx.x * 256 + threadIdx.x;
  if (idx >= n8) return;
  size_t base = (size_t)idx * 8;
  const float4* s4 = reinterpret_cast<const float4*>(src + base);
  float4 a = s4[0], b = s4[1];
  short o[8] = { f2b(a.x), f2b(a.y), f2b(a.z), f2b(a.w),
                 f2b(b.x), f2b(b.y), f2b(b.z), f2b(b.w) };
  *reinterpret_cast<ulonglong2*>(dst + base) = *reinterpret_cast<ulonglong2*>(o);
}

// ----------------- weight transpose + convert (W[k][n] -> WT[n][k]) --------
struct TrParams {
  const float* src[8];
  short* dst[8];
  int rows[8];          // K-dim of each weight (cols always 1280)
};
__global__ void k_conv_tr(TrParams p) {
  int z = blockIdx.z;
  int rows = p.rows[z];
  int r0 = blockIdx.y * 32;
  if (r0 >= rows) return;
  const float* src = p.src[z];
  short* dst = p.dst[z];
  __shared__ float tile[32][33];
  int tx = threadIdx.x & 31, ty = threadIdx.x >> 5;  // 32 x 8
  int c = blockIdx.x * 32 + tx;
#pragma unroll
  for (int it = 0; it < 4; ++it)
    tile[ty + it * 8][tx] = src[(size_t)(r0 + ty + it * 8) * 1280 + c];
  __syncthreads();
#pragma unroll
  for (int it = 0; it < 4; ++it) {
    int n = blockIdx.x * 32 + ty + it * 8;
    dst[(size_t)n * rows + r0 + tx] = f2b(tile[tx][ty + it * 8]);
  }
}

// ------------------- bbox masks -> gm[8][4096] + denom[4096] ---------------
__global__ void k_gm(const float* __restrict__ bbox, float* __restrict__ gm,
                     float* __restrict__ dnm) {
  int s = blockIdx.x * 256 + threadIdx.x;
  if (s >= 4096) return;
  int y = s >> 6, x = s & 63;
  gm[s] = 1.0f;
  float dsum = 1.0f;
#pragma unroll
  for (int i = 0; i < 7; ++i) {
    float x0 = bbox[i * 4 + 0], y0 = bbox[i * 4 + 1];
    float x1 = bbox[i * 4 + 2], y1 = bbox[i * 4 + 3];
    float wmin = floorf(1024.f * x0), hmin = floorf(1024.f * y0);
    float wmax = floorf(1024.f * x1), hmax = floorf(1024.f * y1);
    float r = 0.f, cc = 0.f;
#pragma unroll
    for (int t = 0; t < 4; ++t) {
      const int off[4] = {3, 4, 11, 12};
      float py = (float)(16 * y + off[t]);
      float px = (float)(16 * x + off[t]);
      r  += (py >= hmin && py < hmax) ? 0.25f : 0.f;
      cc += (px >= wmin && px < wmax) ? 0.25f : 0.f;
    }
    float val = r * cc * 10.0f;
    gm[(i + 1) * 4096 + s] = val;
    dsum += val;
  }
  dnm[s] = dsum + 1e-6f;
}

// ---------------------- Q projection: 8192x1280 @ 1280x1280 ----------------
__global__ __launch_bounds__(256) void k_qproj(const short* __restrict__ A,
                                               const short* __restrict__ BT,
                                               short* __restrict__ Cq) {
  __shared__ short As[128 * 32];
  __shared__ short Bs[128 * 32];
  int tid = threadIdx.x, lane = tid & 63, wid = tid >> 6;
  int m0 = blockIdx.x * 128, n0 = blockIdx.y * 128;
  int wr = wid >> 1, wc = wid & 1;
  int colc = lane & 15, g4 = lane >> 4;
  int ar = lane >> 2, ac = (lane & 3) * 8;
  f32x4 acc[4][4] = {};
  for (int kt = 0; kt < 40; ++kt) {
    int k0 = kt * 32;
#pragma unroll
    for (int i = 0; i < 2; ++i) {
      int row = wid * 16 + i * 64 + ar;
      gload16(A + (size_t)(m0 + row) * 1280 + k0 + ac, &As[wid * 512 + i * 2048]);
      gload16(BT + (size_t)(n0 + row) * 1280 + k0 + ac, &Bs[wid * 512 + i * 2048]);
    }
    __syncthreads();
    bf16x8 af[4], bfr[4];
#pragma unroll
    for (int m = 0; m < 4; ++m)
      af[m] = ldb8(&As[(wr * 64 + 16 * m + colc) * 32 + 8 * g4]);
#pragma unroll
    for (int n = 0; n < 4; ++n)
      bfr[n] = ldb8(&Bs[(wc * 64 + 16 * n + colc) * 32 + 8 * g4]);
#pragma unroll
    for (int m = 0; m < 4; ++m)
#pragma unroll
      for (int n = 0; n < 4; ++n)
        acc[m][n] = MFMA16(af[m], bfr[n], acc[m][n]);
    __syncthreads();
  }
#pragma unroll
  for (int m = 0; m < 4; ++m)
#pragma unroll
    for (int n = 0; n < 4; ++n)
#pragma unroll
      for (int r = 0; r < 4; ++r) {
        int row = m0 + wr * 64 + 16 * m + 4 * g4 + r;
        int col = n0 + wc * 64 + 16 * n + colc;
        Cq[(size_t)row * 1280 + col] = f2b(acc[m][n][r]);
      }
}

// ------------- ctx + local K/V projections (1-wave blocks, 16x64 tiles) ----
__global__ __launch_bounds__(64) void k_projkv(
    const short* __restrict__ ctxb, const short* __restrict__ lfb,
    const short* __restrict__ WkT, const short* __restrict__ WvT,
    const short* __restrict__ WkgT, const short* __restrict__ WvgT,
    const short* __restrict__ WklT, const short* __restrict__ WvlT,
    short* __restrict__ kbuf, short* __restrict__ vTb,
    short* __restrict__ klbuf, short* __restrict__ vlTb,
    const int* __restrict__ lidx) {
  int z = blockIdx.z, yt = blockIdx.y, c0 = blockIdx.x * 64;
  int lane = threadIdx.x;
  int colc = lane & 15, g4 = lane >> 4;
  const short *Ab, *Wk_, *Wv_;
  int R;
  if (z < NSTR) {
    if (yt >= 5) return;
    R = GK;
    Ab = ctxb + (size_t)z * GK * CCH;
    bool useg = (z > 0) && (lidx[z - 1] >= 0);
    Wk_ = useg ? WkgT : WkT;
    Wv_ = useg ? WvgT : WvT;
  } else {
    R = LKEY;
    Ab = lfb + (size_t)(z - NSTR) * LKEY * CCH;
    Wk_ = WklT; Wv_ = WvlT;
  }
  int rowA = yt * 16 + colc;
  if (rowA >= R) rowA = R - 1;
  f32x4 ak[4] = {}, av[4] = {};
  for (int kk = 0; kk < 24; ++kk) {
    bf16x8 af = ldb8(&Ab[(size_t)rowA * CCH + kk * 32 + 8 * g4]);
#pragma unroll
    for (int nt = 0; nt < 4; ++nt) {
      bf16x8 bk = ldb8(&Wk_[(size_t)(c0 + 16 * nt + colc) * CCH + kk * 32 + 8 * g4]);
      ak[nt] = MFMA16(af, bk, ak[nt]);
      bf16x8 bv = ldb8(&Wv_[(size_t)(c0 + 16 * nt + colc) * CCH + kk * 32 + 8 * g4]);
      av[nt] = MFMA16(af, bv, av[nt]);
    }
  }
#pragma unroll
  for (int nt = 0; nt < 4; ++nt)
#pragma unroll
    for (int r = 0; r < 4; ++r) {
      int row = yt * 16 + 4 * g4 + r;
      if (row < R) {
        int col = c0 + 16 * nt + colc;
        int hh = col / 160, dd = col % 160;
        short kv = f2b(ak[nt][r]), vv = f2b(av[nt][r]);
        if (z < NSTR) {
          size_t kb = (size_t)(z * 8 + hh) * KGB +
                      (size_t)((row * 320 + 2 * dd) ^ ((row & 7) << 4));
          *(short*)((char*)kbuf + kb) = kv;
          size_t vb = (size_t)(z * 8 + hh) * VGB +
                      (size_t)((dd * 192 + 2 * row) ^ ((dd & 7) << 4));
          *(short*)((char*)vTb + vb) = vv;
        } else {
          int ii = z - NSTR;
          size_t kb = (size_t)(ii * 8 + hh) * KLB +
                      (size_t)((row * 320 + 2 * dd) ^ ((row & 7) << 4));
          *(short*)((char*)klbuf + kb) = kv;
          // V^T in 64-key chunks: [chunk][d][unit^(d&7)][key&7], contiguous
          // per chunk so k_attnl can global_load_lds it linearly.
          int cc = row >> 6, lc = row & 63;
          int unit = lc >> 3, wi = lc & 7;
          vlTb[((size_t)(ii * 8 + hh) * 5 + cc) * 10240 + dd * 64 +
               ((unit ^ (dd & 7)) << 3) + wi] = vv;
        }
      }
    }
}

// ----------------------------- global attention ----------------------------
__global__ __launch_bounds__(256) void k_attng(
    const short* __restrict__ q, const short* __restrict__ kb_,
    const short* __restrict__ vT, short* __restrict__ abh,
    float* __restrict__ mg, const int* __restrict__ lidx) {
  int chunk = blockIdx.x, h = blockIdx.y, b = blockIdx.z;
  int tid = threadIdx.x, lane = tid & 63, wid = tid >> 6;
  __shared__ short KV[28160];                 // K: [0,12800) V: [12800,28160)
  alignas(16) __shared__ short pbuf[4][16 * 104];
  const short* qb = q + (b > 0 ? (size_t)S_LEN * CH : 0) + h * HD;
  const short* kg = kb_ + (size_t)(b * 8 + h) * (KGB / 2);
  const short* vg = vT + (size_t)(b * 8 + h) * (VGB / 2);
  for (int j = wid; j < 55; j += 4) {
    if (j < 25) gload16(kg + j * 512 + (lane << 3), &KV[j * 512]);
    else        gload16(vg + (j - 25) * 512 + (lane << 3), &KV[12800 + (j - 25) * 512]);
  }
  __syncthreads();
  short* pw = pbuf[wid];
  int colc = lane & 15, g4 = lane >> 4;
  int xorv = (colc & 7) << 4;
  const float scale = 0.07905694150420949f;  // 1/sqrt(160)
  int li[8];
#pragma unroll
  for (int i = 0; i < 8; ++i) li[i] = lidx[i];

  for (int g = 0; g < 8; ++g) {
    int s0 = chunk * 512 + wid * 128 + g * 16;
    bf16x8 aq[5];
#pragma unroll
    for (int kk = 0; kk < 5; ++kk)
      aq[kk] = ldb8(&qb[(size_t)(s0 + colc) * CH + kk * 32 + 8 * g4]);
    f32x4 acc[5] = {};
#pragma unroll
    for (int nt = 0; nt < 5; ++nt)
#pragma unroll
      for (int kk = 0; kk < 5; ++kk) {
        int kbx = (((16 * nt + colc) * 320 + 64 * kk + 16 * g4) ^ xorv) >> 1;
        acc[nt] = MFMA16(aq[kk], ldb8(&KV[kbx]), acc[nt]);
      }
    // ---- softmax over 77 keys ----
    float rmax[4] = {-1e30f, -1e30f, -1e30f, -1e30f};
#pragma unroll
    for (int nt = 0; nt < 5; ++nt) {
      bool v = (16 * nt + colc) < GK;
#pragma unroll
      for (int r = 0; r < 4; ++r) {
        float lg = v ? acc[nt][r] * scale : -1e30f;
        acc[nt][r] = lg;
        rmax[r] = fmaxf(rmax[r], lg);
      }
    }
#pragma unroll
    for (int r = 0; r < 4; ++r)
#pragma unroll
      for (int m = 1; m < 16; m <<= 1) rmax[r] = fmaxf(rmax[r], __shfl_xor(rmax[r], m, 64));
    float rsum[4] = {0.f, 0.f, 0.f, 0.f};
#pragma unroll
    for (int nt = 0; nt < 5; ++nt) {
      bool v = (16 * nt + colc) < GK;
#pragma unroll
      for (int r = 0; r < 4; ++r) {
        float p = v ? __expf(acc[nt][r] - rmax[r]) : 0.0f;
        acc[nt][r] = p;
        rsum[r] += p;
      }
    }
#pragma unroll
    for (int r = 0; r < 4; ++r)
#pragma unroll
      for (int m = 1; m < 16; m <<= 1) rsum[r] += __shfl_xor(rsum[r], m, 64);
    float rinv[4];
#pragma unroll
    for (int r = 0; r < 4; ++r) rinv[r] = 1.0f / rsum[r];
#pragma unroll
    for (int nt = 0; nt < 5; ++nt)
#pragma unroll
      for (int r = 0; r < 4; ++r) acc[nt][r] *= rinv[r];
    // ---- gate capture (stream 0): m[i][h][s] = probs[s][local_index[i]]
    if (b == 0) {
#pragma unroll
      for (int i = 0; i < 8; ++i) {
        int l_ = li[i];
        float pv[4] = {0.f, 0.f, 0.f, 0.f};
#pragma unroll
        for (int nt = 0; nt < 5; ++nt)
#pragma unroll
          for (int r = 0; r < 4; ++r)
            pv[r] = (nt == (l_ >> 4)) ? acc[nt][r] : pv[r];
        if ((l_ & 15) == colc) {
#pragma unroll
          for (int r = 0; r < 4; ++r)
            mg[(size_t)(i * NHEAD + h) * 4096 + s0 + 4 * g4 + r] = pv[r];
        }
      }
    }
    // ---- P -> per-wave LDS (96 cols, tile 5 zero-padded) ----
#pragma unroll
    for (int nt = 0; nt < 6; ++nt)
#pragma unroll
      for (int r = 0; r < 4; ++r) {
        short vb = (nt < 5) ? f2b(acc[nt][r]) : (short)0;
        pw[(4 * g4 + r) * 104 + 16 * nt + colc] = vb;
      }
    // ---- PV from LDS ----
    f32x4 acc2[10] = {};
#pragma unroll
    for (int kk2 = 0; kk2 < 3; ++kk2) {
      bf16x8 ap = ldb8(&pw[colc * 104 + kk2 * 32 + 8 * g4]);
#pragma unroll
      for (int nt2 = 0; nt2 < 10; ++nt2) {
        int vbx = 12800 + (((((16 * nt2 + colc) * 192) + 64 * kk2 + 16 * g4) ^ xorv) >> 1);
        acc2[nt2] = MFMA16(ap, ldb8(&KV[vbx]), acc2[nt2]);
      }
    }
#pragma unroll
    for (int nt2 = 0; nt2 < 10; ++nt2)
#pragma unroll
      for (int r = 0; r < 4; ++r) {
        int s = s0 + 4 * g4 + r;
        abh[((size_t)b * S_LEN + s) * CH + h * HD + 16 * nt2 + colc] = f2b(acc2[nt2][r]);
      }
  }
}

// --------------------- gate max reduce: mmax[i] = max(mg[i]) ---------------
__global__ __launch_bounds__(256) void k_mmax(const float* __restrict__ mg,
                                              float* __restrict__ mmx) {
  int i = blockIdx.x;
  __shared__ float red[4];
  float m = 0.f;
  for (int t = threadIdx.x; t < 32768; t += 256) m = fmaxf(m, mg[(size_t)i * 32768 + t]);
#pragma unroll
  for (int msk = 32; msk >= 1; msk >>= 1) m = fmaxf(m, __shfl_xor(m, msk, 64));
  if ((threadIdx.x & 63) == 0) red[threadIdx.x >> 6] = m;
  __syncthreads();
  if (threadIdx.x == 0)
    mmx[i] = fmaxf(fmaxf(red[0], red[1]), fmaxf(red[2], red[3]));
}

// ------------------------------ local attention ----------------------------
// K staged once (87 KB swizzled); V^T double-buffered in LDS as 5 x 20 KB
// pre-swizzled 64-key chunks. pbuf per-wave 16x72. 8 waves, 8 slabs.
__global__ __launch_bounds__(512) void k_attnl(
    const short* __restrict__ q, const short* __restrict__ klb_,
    const short* __restrict__ vlT, short* __restrict__ abh,
    const float* __restrict__ mg, const float* __restrict__ mmx) {
  int chunk = blockIdx.x, h = blockIdx.y, i = blockIdx.z;
  int tid = threadIdx.x, lane = tid & 63, wid = tid >> 6;
  __shared__ short Klds[43520];               // 272 rows x 160 d, swizzled
  __shared__ short Vlds[2][10240];            // 2 x [160 d][64 keys], swizzled
  alignas(16) __shared__ short pbuf[8][16 * 72];
  const short* qb = q + (size_t)S_LEN * CH + h * HD;  // batch-1 Q
  const short* kg = klb_ + (size_t)(i * 8 + h) * (KLB / 2);
  const short* vtb = vlT + (size_t)(i * 8 + h) * (VLB / 2);
  for (int j = wid; j < 85; j += 8) gload16(kg + j * 512 + (lane << 3), &Klds[j * 512]);
  // prologue: stage V chunk 0 into buffer 0
  for (int u0 = wid * 64; u0 < 1280; u0 += 512)
    gload16(vtb + (u0 << 3) + (lane << 3), &Vlds[0][u0 << 3]);
  __syncthreads();
  short* pw = pbuf[wid];
  int colc = lane & 15, g4 = lane >> 4;
  int xorv = (colc & 7) << 4;
  const float scale = 0.07905694150420949f;
  float minv = 1.0f / mmx[i];
  int cur = 0;

  for (int g = 0; g < 8; ++g) {
    int s0 = chunk * 1024 + wid * 128 + g * 16;
    bf16x8 aq[5];
#pragma unroll
    for (int kk = 0; kk < 5; ++kk)
      aq[kk] = ldb8(&qb[(size_t)(s0 + colc) * CH + kk * 32 + 8 * g4]);
    f32x4 acc[17] = {};
#pragma unroll
    for (int nt = 0; nt < 17; ++nt)
#pragma unroll
      for (int kk = 0; kk < 5; ++kk) {
        int kbx = (((16 * nt + colc) * 320 + 64 * kk + 16 * g4) ^ xorv) >> 1;
        acc[nt] = MFMA16(aq[kk], ldb8(&Klds[kbx]), acc[nt]);
      }
    float rmax[4] = {-1e30f, -1e30f, -1e30f, -1e30f};
#pragma unroll
    for (int nt = 0; nt < 17; ++nt) {
      bool v = (16 * nt + colc) < LKEY;
#pragma unroll
      for (int r = 0; r < 4; ++r) {
        float lg = v ? acc[nt][r] * scale : -1e30f;
        acc[nt][r] = lg;
        rmax[r] = fmaxf(rmax[r], lg);
      }
    }
#pragma unroll
    for (int r = 0; r < 4; ++r)
#pragma unroll
      for (int m = 1; m < 16; m <<= 1) rmax[r] = fmaxf(rmax[r], __shfl_xor(rmax[r], m, 64));
    float rsum[4] = {0.f, 0.f, 0.f, 0.f};
#pragma unroll
    for (int nt = 0; nt < 17; ++nt) {
      bool v = (16 * nt + colc) < LKEY;
#pragma unroll
      for (int r = 0; r < 4; ++r) {
        float p = v ? __expf(acc[nt][r] - rmax[r]) : 0.0f;
        acc[nt][r] = p;
        rsum[r] += p;
      }
    }
#pragma unroll
    for (int r = 0; r < 4; ++r)
#pragma unroll
      for (int m = 1; m < 16; m <<= 1) rsum[r] += __shfl_xor(rsum[r], m, 64);
    float rinv[4];
#pragma unroll
    for (int r = 0; r < 4; ++r) rinv[r] = 1.0f / rsum[r];

    // PV over 5 x 64-key chunks, double-buffered V in LDS.
    f32x4 acc2[10] = {};
#pragma unroll
    for (int c = 0; c < 5; ++c) {
      {
        const short* srcv = vtb + (c == 4 ? 0 : (c + 1)) * 10240;
        for (int u0 = wid * 64; u0 < 1280; u0 += 512)
          gload16(srcv + (u0 << 3) + (lane << 3), &Vlds[cur ^ 1][u0 << 3]);
      }
#pragma unroll
      for (int t = 0; t < 4; ++t) {
        int nt = 4 * c + t;
#pragma unroll
        for (int r = 0; r < 4; ++r) {
          short vb = (nt < 17) ? f2b(acc[nt][r] * rinv[r]) : (short)0;
          pw[(4 * g4 + r) * 72 + 16 * t + colc] = vb;
        }
      }
#pragma unroll
      for (int kc = 0; kc < 2; ++kc) {
        bf16x8 ap = ldb8(&pw[colc * 72 + kc * 32 + 8 * g4]);
#pragma unroll
        for (int nt2 = 0; nt2 < 10; ++nt2) {
          bf16x8 bv = ldb8(&Vlds[cur][(16 * nt2 + colc) * 64 +
                                      ((((kc << 2) + g4) ^ (colc & 7)) << 3)]);
          acc2[nt2] = MFMA16(ap, bv, acc2[nt2]);
        }
      }
      __syncthreads();
      cur ^= 1;
    }
    float gv[4];
#pragma unroll
    for (int r = 0; r < 4; ++r)
      gv[r] = mg[(size_t)(i * NHEAD + h) * 4096 + s0 + 4 * g4 + r] * minv;
#pragma unroll
    for (int nt2 = 0; nt2 < 10; ++nt2)
#pragma unroll
      for (int r = 0; r < 4; ++r) {
        int s = s0 + 4 * g4 + r;
        size_t idx = ((size_t)(1 + i) * S_LEN + s) * CH + h * HD + 16 * nt2 + colc;
        float oldv = b2f(abh[idx]);
        abh[idx] = f2b(0.5f * oldv + 0.5f * gv[r] * acc2[nt2][r]);
      }
  }
}

// ------------- out projection + fused bbox fuser epilogue ------------------
// R6: 768 threads, 12 waves = 3 groups x (2x2 waves) on one 64x128 tile.
// Per K-step (BK=64): stage ALL 9 stream A-tiles (72 KB, XOR-swz) + B once
// (16 KB, XOR-swz); group g computes streams {3g,3g+1,3g+2} with B-frags
// read once and reused across the 3 passes. 2 barriers per K-step.
// XOR swizzle both-sides: source column ^ (row&7), read column ^ (colc&7).
__global__ __launch_bounds__(768, 3) void k_outproj(
    const short* __restrict__ abh, const short* __restrict__ WoT,
    const float* __restrict__ bout, const float* __restrict__ gm,
    const float* __restrict__ dnm, float* __restrict__ outp) {
  __shared__ __align__(16) char smem[90112];
  short* As = (short*)smem;             // 9 x [64][64] shorts (72 KB), swizzled
  short* Bs = (short*)(smem + 73728);   // [128][64] shorts (16 KB), swizzled
  float* comb = (float*)smem;           // epilogue overlay [64][128] f32 (32 KB)
  int tid = threadIdx.x, lane = tid & 63, wid = tid >> 6;
  int g = wid >> 2, gw4 = wid & 3;      // wave-group (stream triple), wave idx
  int wr = gw4 >> 1, wc = gw4 & 1;      // 2x2 wave layout over 64x128
  int s0 = blockIdx.x * 64, n0 = blockIdx.y * 128;
  int colc = lane & 15, g4 = lane >> 4;
  int ar = lane >> 3;
  int acs = (((lane & 7) ^ ar) << 3);   // XOR-pre-swizzled source col (shorts)
  int swz = (colc & 7) << 3;            // read-side XOR (shorts)
  float bo[4];
#pragma unroll
  for (int nt = 0; nt < 4; ++nt) bo[nt] = bout[n0 + wc * 64 + 16 * nt + colc];
  f32x4 acc[3][2][4] = {};
  for (int kt = 0; kt < 20; ++kt) {
    int k0 = kt * 64;
    // stage 9 A-tiles (72 instrs) + B (16 instrs) across 12 waves
    for (int j = wid; j < 88; j += 12) {
      if (j < 72) {
        int t = j >> 3, r8 = j & 7;
        gload16(abh + ((size_t)t * S_LEN + s0 + r8 * 8 + ar) * CH + k0 + acs,
                As + t * 4096 + r8 * 512);
      } else {
        int jb = j - 72;
        gload16(WoT + (size_t)(n0 + jb * 8 + ar) * 1280 + k0 + acs, Bs + jb * 512);
      }
    }
    __syncthreads();
    bf16x8 bfr[4][2];
#pragma unroll
    for (int nt = 0; nt < 4; ++nt)
#pragma unroll
      for (int kk = 0; kk < 2; ++kk)
        bfr[nt][kk] = ldb8(&Bs[(wc * 64 + 16 * nt + colc) * 64 +
                               ((kk * 32 + 8 * g4) ^ swz)]);
#pragma unroll
    for (int p = 0; p < 3; ++p) {
      bf16x8 af[2][2];
#pragma unroll
      for (int mt = 0; mt < 2; ++mt)
#pragma unroll
        for (int kk = 0; kk < 2; ++kk)
          af[mt][kk] = ldb8(&As[(3 * g + p) * 4096 + (wr * 32 + 16 * mt + colc) * 64 +
                                ((kk * 32 + 8 * g4) ^ swz)]);
#pragma unroll
      for (int mt = 0; mt < 2; ++mt)
#pragma unroll
        for (int nt = 0; nt < 4; ++nt)
#pragma unroll
          for (int kk = 0; kk < 2; ++kk)
            acc[p][mt][nt] = MFMA16(af[mt][kk], bfr[nt][kk], acc[p][mt][nt]);
    }
    __syncthreads();
  }
  // epilogue: stream 0 direct; streams 1..8 gm-weighted into fac
  f32x4 fac[2][4] = {};
#pragma unroll
  for (int p = 0; p < 3; ++p) {
    int b = 3 * g + p;
    if (b == 0) {
#pragma unroll
      for (int mt = 0; mt < 2; ++mt)
#pragma unroll
        for (int nt = 0; nt < 4; ++nt)
#pragma unroll
          for (int r = 0; r < 4; ++r) {
            int s = s0 + wr * 32 + 16 * mt + 4 * g4 + r;
            int c = n0 + wc * 64 + 16 * nt + colc;
            outp[(size_t)s * CH + c] = acc[p][mt][nt][r] + bo[nt];
          }
    } else {
      float gwv[2][4];
#pragma unroll
      for (int mt = 0; mt < 2; ++mt)
#pragma unroll
        for (int r = 0; r < 4; ++r)
          gwv[mt][r] = gm[(size_t)(b - 1) * 4096 + s0 + wr * 32 + 16 * mt + 4 * g4 + r];
#pragma unroll
      for (int mt = 0; mt < 2; ++mt)
#pragma unroll
        for (int nt = 0; nt < 4; ++nt)
#pragma unroll
          for (int r = 0; r < 4; ++r)
            fac[mt][nt][r] += gwv[mt][r] * acc[p][mt][nt][r];
    }
  }
  // combine group1/group2 partials into group0 via LDS overlay
#pragma unroll 1
  for (int src = 1; src <= 2; ++src) {
    if (g == src) {
#pragma unroll
      for (int mt = 0; mt < 2; ++mt)
#pragma unroll
        for (int nt = 0; nt < 4; ++nt)
#pragma unroll
          for (int r = 0; r < 4; ++r)
            comb[(wr * 32 + 16 * mt + 4 * g4 + r) * 128 + wc * 64 + 16 * nt + colc] =
                fac[mt][nt][r];
    }
    __syncthreads();
    if (g == 0) {
#pragma unroll
      for (int mt = 0; mt < 2; ++mt)
#pragma unroll
        for (int nt = 0; nt < 4; ++nt)
#pragma unroll
          for (int r = 0; r < 4; ++r)
            fac[mt][nt][r] +=
                comb[(wr * 32 + 16 * mt + 4 * g4 + r) * 128 + wc * 64 + 16 * nt + colc];
    }
    __syncthreads();
  }
  if (g == 0) {
#pragma unroll
    for (int mt = 0; mt < 2; ++mt)
#pragma unroll
      for (int r = 0; r < 4; ++r) {
        int s = s0 + wr * 32 + 16 * mt + 4 * g4 + r;
        float dn = dnm[s];
        float sw = dn - 1e-6f;
        float inv = 1.0f / dn;
#pragma unroll
        for (int nt = 0; nt < 4; ++nt) {
          int c = n0 + wc * 64 + 16 * nt + colc;
          outp[(size_t)(S_LEN + s) * CH + c] = (fac[mt][nt][r] + bo[nt] * sw) * inv;
        }
      }
  }
}

// ---------------------------------------------------------------------------
extern "C" void kernel_launch(void* const* d_in, const int* in_sizes, int n_in,
                              void* d_out, int out_size, void* d_ws, size_t ws_size,
                              hipStream_t stream) {
  const float* hs   = (const float*)d_in[0];
  const float* ctx  = (const float*)d_in[1];
  const float* lf   = (const float*)d_in[2];
  const float* bbox = (const float*)d_in[3];
  const float* Wq   = (const float*)d_in[4];
  const float* Wk   = (const float*)d_in[5];
  const float* Wv   = (const float*)d_in[6];
  const float* Wkg  = (const float*)d_in[7];
  const float* Wvg  = (const float*)d_in[8];
  const float* Wkl  = (const float*)d_in[9];
  const float* Wvl  = (const float*)d_in[10];
  const float* Wout = (const float*)d_in[11];
  const float* bo   = (const float*)d_in[12];
  const int*   lidx = (const int*)d_in[13];
  float* outp = (float*)d_out;

  char* w = (char*)d_ws;
  size_t off = 0;
  auto carve = [&](size_t bytes) {
    char* p = w + off;
    off = (off + bytes + 255) & ~(size_t)255;
    return p;
  };
  short* hsb   = (short*)carve(2ull * S_LEN * CH * 2);
  short* qbuf  = (short*)carve(2ull * S_LEN * CH * 2);
  short* WqT   = (short*)carve(1280ull * 1280 * 2);
  short* WoT   = (short*)carve(1280ull * 1280 * 2);
  short* WkT   = (short*)carve(1280ull * 768 * 2);
  short* WvT   = (short*)carve(1280ull * 768 * 2);
  short* WkgT  = (short*)carve(1280ull * 768 * 2);
  short* WvgT  = (short*)carve(1280ull * 768 * 2);
  short* WklT  = (short*)carve(1280ull * 768 * 2);
  short* WvlT  = (short*)carve(1280ull * 768 * 2);
  short* ctxb  = (short*)carve((size_t)NSTR * GK * CCH * 2);
  short* lfb   = (short*)carve((size_t)NLOC * LKEY * CCH * 2);
  short* kbuf  = (short*)carve((size_t)NSTR * 8 * KGB);
  short* klbuf = (short*)carve((size_t)NLOC * 8 * KLB);
  short* vTb   = (short*)carve((size_t)NSTR * 8 * VGB);
  short* vlTb  = (short*)carve((size_t)NLOC * 8 * VLB);
  short* abh   = (short*)carve((size_t)NSTR * S_LEN * CH * 2);
  float* mg    = (float*)carve(8ull * 8 * 4096 * 4);
  float* mmx   = (float*)carve(256);
  float* gmb   = (float*)carve(8ull * 4096 * 4);
  float* dnm   = (float*)carve(4096ull * 4);
  (void)carve(65536);  // slack
  if (off > ws_size) {
    fprintf(stderr, "MIGC kernel: ws too small, need %zu have %zu\n", off, ws_size);
    return;
  }

  hipMemsetAsync(vTb, 0, (size_t)NSTR * 8 * VGB, stream);
  hipMemsetAsync(vlTb, 0, (size_t)NLOC * 8 * VLB, stream);

  k_conv_flat<<<5120, 256, 0, stream>>>(hs, hsb, 1310720);
  k_conv_flat<<<260, 256, 0, stream>>>(ctx, ctxb, 66528);
  k_conv_flat<<<771, 256, 0, stream>>>(lf, lfb, 197376);

  TrParams tp;
  const float* srcs[8] = {Wq, Wk, Wv, Wkg, Wvg, Wkl, Wvl, Wout};
  short* dsts[8] = {WqT, WkT, WvT, WkgT, WvgT, WklT, WvlT, WoT};
  int rws[8] = {1280, 768, 768, 768, 768, 768, 768, 1280};
  for (int i = 0; i < 8; ++i) { tp.src[i] = srcs[i]; tp.dst[i] = dsts[i]; tp.rows[i] = rws[i]; }
  k_conv_tr<<<dim3(40, 40, 8), 256, 0, stream>>>(tp);

  k_gm<<<16, 256, 0, stream>>>(bbox, gmb, dnm);
  k_qproj<<<dim3(64, 10), 256, 0, stream>>>(hsb, WqT, qbuf);
  k_projkv<<<dim3(20, 17, 17), 64, 0, stream>>>(ctxb, lfb, WkT, WvT, WkgT, WvgT,
                                                WklT, WvlT, kbuf, vTb, klbuf, vlTb, lidx);
  k_attng<<<dim3(8, 8, 9), 256, 0, stream>>>(qbuf, kbuf, vTb, abh, mg, lidx);
  k_mmax<<<8, 256, 0, stream>>>(mg, mmx);
  k_attnl<<<dim3(4, 8, 8), 512, 0, stream>>>(qbuf, klbuf, vlTb, abh, mg, mmx);
  k_outproj<<<dim3(64, 10), 768, 0, stream>>>(abh, WoT, bo, gmb, dnm, outp);
}